// Round 1
// baseline (5232.862 us; speedup 1.0000x reference)
//
#include <hip/hip_runtime.h>
#include <cstdint>
#include <cstddef>

#define B_   4
#define S_   2048
#define D_   2048
#define NH_  16
#define NKV_ 4
#define HD_  128

// ---------------------------------------------------------------------------
// SGEMM: C[M,N] = A[M,K] @ W[N,K]^T + bias   (A row-major, W row-major [N,K])
// 128x128 block tile, BK=16, 256 threads, 8x8 per-thread micro-tile.
// ---------------------------------------------------------------------------
__global__ __launch_bounds__(256) void sgemm_bt(
    const float* __restrict__ A, const float* __restrict__ W,
    const float* __restrict__ bias, float* __restrict__ C,
    int M, int N, int K)
{
    __shared__ float As[16][128];
    __shared__ float Bs[16][128];

    const int tid = threadIdx.x;
    const int tx  = tid & 15;   // col group 0..15
    const int ty  = tid >> 4;   // row group 0..15
    const int bm  = blockIdx.y * 128;
    const int bn  = blockIdx.x * 128;

    const int lr = tid >> 1;        // 0..127 (tile row for loading)
    const int lc = (tid & 1) * 8;   // 0 or 8 (k-col for loading)
    const float* Ap = A + (size_t)(bm + lr) * K + lc;
    const float* Wp = W + (size_t)(bn + lr) * K + lc;

    float acc[8][8];
#pragma unroll
    for (int i = 0; i < 8; ++i)
#pragma unroll
        for (int j = 0; j < 8; ++j) acc[i][j] = 0.f;

    for (int k0 = 0; k0 < K; k0 += 16) {
        float4 a0 = *(const float4*)(Ap + k0);
        float4 a1 = *(const float4*)(Ap + k0 + 4);
        float4 w0 = *(const float4*)(Wp + k0);
        float4 w1 = *(const float4*)(Wp + k0 + 4);

        As[lc+0][lr] = a0.x; As[lc+1][lr] = a0.y; As[lc+2][lr] = a0.z; As[lc+3][lr] = a0.w;
        As[lc+4][lr] = a1.x; As[lc+5][lr] = a1.y; As[lc+6][lr] = a1.z; As[lc+7][lr] = a1.w;
        Bs[lc+0][lr] = w0.x; Bs[lc+1][lr] = w0.y; Bs[lc+2][lr] = w0.z; Bs[lc+3][lr] = w0.w;
        Bs[lc+4][lr] = w1.x; Bs[lc+5][lr] = w1.y; Bs[lc+6][lr] = w1.z; Bs[lc+7][lr] = w1.w;
        __syncthreads();

#pragma unroll
        for (int kk = 0; kk < 16; ++kk) {
            float4 x0 = *(const float4*)&As[kk][ty*8];
            float4 x1 = *(const float4*)&As[kk][ty*8+4];
            float4 y0 = *(const float4*)&Bs[kk][tx*8];
            float4 y1 = *(const float4*)&Bs[kk][tx*8+4];
            float av[8] = {x0.x,x0.y,x0.z,x0.w,x1.x,x1.y,x1.z,x1.w};
            float bv[8] = {y0.x,y0.y,y0.z,y0.w,y1.x,y1.y,y1.z,y1.w};
#pragma unroll
            for (int i = 0; i < 8; ++i)
#pragma unroll
                for (int j = 0; j < 8; ++j)
                    acc[i][j] = fmaf(av[i], bv[j], acc[i][j]);
        }
        __syncthreads();
    }

    float bb[8];
#pragma unroll
    for (int j = 0; j < 8; ++j) bb[j] = bias ? bias[bn + tx*8 + j] : 0.f;

#pragma unroll
    for (int i = 0; i < 8; ++i) {
        float* Cp = C + (size_t)(bm + ty*8 + i) * N + bn + tx*8;
        *(float4*)(Cp)   = make_float4(acc[i][0]+bb[0], acc[i][1]+bb[1],
                                       acc[i][2]+bb[2], acc[i][3]+bb[3]);
        *(float4*)(Cp+4) = make_float4(acc[i][4]+bb[4], acc[i][5]+bb[5],
                                       acc[i][6]+bb[6], acc[i][7]+bb[7]);
    }
}

// ---------------------------------------------------------------------------
// RoPE in place on tensor [B*S, H, 128]. One 128-thread half-block per row.
// ---------------------------------------------------------------------------
__global__ __launch_bounds__(256) void rope_kernel(float* __restrict__ t, int H)
{
    const int tid = threadIdx.x;
    const int rid = blockIdx.x * 2 + (tid >> 7);   // row id in [0, B*S*H)
    const int d   = tid & 127;
    const int s   = (rid / H) & (S_ - 1);          // sequence position
    const int j   = d & 63;

    // inv_freq = 1 / base^(2j/128), mimic reference fp32 arithmetic
    float inv  = 1.0f / powf(1.0e6f, (float)j * (1.0f / 64.0f));
    float freq = (float)s * inv;
    float sn, cs;
    sincosf(freq, &sn, &cs);

    size_t base = (size_t)rid * HD_;
    float x0 = t[base + d];
    float xp = t[base + (d ^ 64)];
    float rot = (d < 64) ? -xp : xp;
    __syncthreads();                // all reads of this row done before writes
    t[base + d] = fmaf(x0, cs, rot * sn);
}

// ---------------------------------------------------------------------------
// Causal flash attention, GQA (4 q-heads per kv-head).
// Q: [B,S,NH,HD]  K,V: [B,S,NKV,HD]  ctx out: [B,S,NH,HD]
// One 256-thread block per (b, h, 32-row q tile). 32x32 K/V tiles.
// LDS: 3*32*132*4 + 32*35*4 + 3*128 = ~55.5 KB  (<64 KB static limit)
// ---------------------------------------------------------------------------
__device__ inline float dot4(float4 a, float4 b, float c) {
    c = fmaf(a.x, b.x, c); c = fmaf(a.y, b.y, c);
    c = fmaf(a.z, b.z, c); return fmaf(a.w, b.w, c);
}

__global__ __launch_bounds__(256) void flash_attn(
    const float* __restrict__ Q, const float* __restrict__ K,
    const float* __restrict__ V, float* __restrict__ ctx)
{
    __shared__ float Qs[32][132];   // +4 pad: conflict-free f4 reads
    __shared__ float Ks[32][132];
    __shared__ float Vs[32][132];
    __shared__ float Ps[32][35];    // +3 pad: stride 35 coprime-ish with 32
    __shared__ float m_s[32], l_s[32], a_s[32];

    const int tid = threadIdx.x;
    const int tx  = tid & 15;       // S-tile col group  (cols tx, tx+16)
    const int ty  = tid >> 4;       // S-tile row group  (rows ty, ty+16)
    const int q0  = blockIdx.x * 32;
    const int h   = blockIdx.y;
    const int b   = blockIdx.z;
    const int kvh = h >> 2;         // GROUPS = 4 (repeat_interleave)
    const float scale = 0.08838834764831845f;   // 1/sqrt(128)

    // ---- load Q tile, pre-scaled ----
    for (int idx = tid * 4; idx < 32 * 128; idx += 1024) {
        int r = idx >> 7, d = idx & 127;
        float4 qv = *(const float4*)&Q[(((size_t)b * S_ + q0 + r) * NH_ + h) * HD_ + d];
        *(float4*)&Qs[r][d] = make_float4(qv.x*scale, qv.y*scale, qv.z*scale, qv.w*scale);
    }
    if (tid < 32) { m_s[tid] = -3.0e38f; l_s[tid] = 0.f; }

    float o[2][8];
#pragma unroll
    for (int r = 0; r < 2; ++r)
#pragma unroll
        for (int c = 0; c < 8; ++c) o[r][c] = 0.f;

    const int ntiles = (q0 >> 5) + 1;
    for (int t = 0; t < ntiles; ++t) {
        const int k0 = t * 32;
        __syncthreads();   // previous tile's Ps/Vs reads done; Q stores done (t=0)

        // ---- load K/V tile ----
        for (int idx = tid * 4; idx < 32 * 128; idx += 1024) {
            int r = idx >> 7, d = idx & 127;
            size_t g = (((size_t)b * S_ + k0 + r) * NKV_ + kvh) * HD_ + d;
            *(float4*)&Ks[r][d] = *(const float4*)&K[g];
            *(float4*)&Vs[r][d] = *(const float4*)&V[g];
        }
        __syncthreads();

        // ---- S = Qs . Ks^T  (each thread: rows {ty,ty+16} x cols {tx,tx+16}) ----
        float accs[2][2] = {{0.f, 0.f}, {0.f, 0.f}};
#pragma unroll 8
        for (int d = 0; d < 128; d += 4) {
            float4 qa = *(const float4*)&Qs[ty][d];
            float4 qb = *(const float4*)&Qs[ty+16][d];
            float4 ka = *(const float4*)&Ks[tx][d];
            float4 kb = *(const float4*)&Ks[tx+16][d];
            accs[0][0] = dot4(qa, ka, accs[0][0]);
            accs[0][1] = dot4(qa, kb, accs[0][1]);
            accs[1][0] = dot4(qb, ka, accs[1][0]);
            accs[1][1] = dot4(qb, kb, accs[1][1]);
        }

        // ---- causal mask + stage scores ----
#pragma unroll
        for (int rr = 0; rr < 2; ++rr)
#pragma unroll
            for (int cc = 0; cc < 2; ++cc) {
                int qq = q0 + ty + 16*rr;
                int kk = k0 + tx + 16*cc;
                Ps[ty + 16*rr][tx + 16*cc] = (kk <= qq) ? accs[rr][cc] : -3.0e38f;
            }
        __syncthreads();

        // ---- online softmax row update (thread i owns row i) ----
        if (tid < 32) {
            float mold = m_s[tid], mnew = mold;
#pragma unroll
            for (int jj = 0; jj < 32; ++jj) mnew = fmaxf(mnew, Ps[tid][jj]);
            float alpha = expf(mold - mnew);
            float l = l_s[tid] * alpha;
#pragma unroll
            for (int jj = 0; jj < 32; ++jj) {
                float p = expf(Ps[tid][jj] - mnew);
                Ps[tid][jj] = p;
                l += p;
            }
            m_s[tid] = mnew; l_s[tid] = l; a_s[tid] = alpha;
        }
        __syncthreads();

        // ---- rescale O, accumulate P.V (thread: rows {ty,ty+16} x cols tx*8..) ----
        float al0 = a_s[ty], al1 = a_s[ty + 16];
#pragma unroll
        for (int c = 0; c < 8; ++c) { o[0][c] *= al0; o[1][c] *= al1; }

#pragma unroll 4
        for (int jj = 0; jj < 32; ++jj) {
            float  p0 = Ps[ty][jj];
            float  p1 = Ps[ty + 16][jj];
            float4 v0 = *(const float4*)&Vs[jj][tx*8];
            float4 v1 = *(const float4*)&Vs[jj][tx*8 + 4];
            o[0][0] = fmaf(p0, v0.x, o[0][0]);
            o[0][1] = fmaf(p0, v0.y, o[0][1]);
            o[0][2] = fmaf(p0, v0.z, o[0][2]);
            o[0][3] = fmaf(p0, v0.w, o[0][3]);
            o[0][4] = fmaf(p0, v1.x, o[0][4]);
            o[0][5] = fmaf(p0, v1.y, o[0][5]);
            o[0][6] = fmaf(p0, v1.z, o[0][6]);
            o[0][7] = fmaf(p0, v1.w, o[0][7]);
            o[1][0] = fmaf(p1, v0.x, o[1][0]);
            o[1][1] = fmaf(p1, v0.y, o[1][1]);
            o[1][2] = fmaf(p1, v0.z, o[1][2]);
            o[1][3] = fmaf(p1, v0.w, o[1][3]);
            o[1][4] = fmaf(p1, v1.x, o[1][4]);
            o[1][5] = fmaf(p1, v1.y, o[1][5]);
            o[1][6] = fmaf(p1, v1.z, o[1][6]);
            o[1][7] = fmaf(p1, v1.w, o[1][7]);
        }
    }

    // ---- epilogue: normalize and store ctx in [B,S,NH,HD] ----
    float il0 = 1.0f / l_s[ty];
    float il1 = 1.0f / l_s[ty + 16];
    float* c0 = &ctx[(((size_t)b * S_ + q0 + ty)      * NH_ + h) * HD_ + tx*8];
    float* c1 = &ctx[(((size_t)b * S_ + q0 + ty + 16) * NH_ + h) * HD_ + tx*8];
    *(float4*)(c0)   = make_float4(o[0][0]*il0, o[0][1]*il0, o[0][2]*il0, o[0][3]*il0);
    *(float4*)(c0+4) = make_float4(o[0][4]*il0, o[0][5]*il0, o[0][6]*il0, o[0][7]*il0);
    *(float4*)(c1)   = make_float4(o[1][0]*il1, o[1][1]*il1, o[1][2]*il1, o[1][3]*il1);
    *(float4*)(c1+4) = make_float4(o[1][4]*il1, o[1][5]*il1, o[1][6]*il1, o[1][7]*il1);
}

// ---------------------------------------------------------------------------
extern "C" void kernel_launch(void* const* d_in, const int* in_sizes, int n_in,
                              void* d_out, int out_size, void* d_ws, size_t ws_size,
                              hipStream_t stream)
{
    const float* x    = (const float*)d_in[0];
    const float* wq_w = (const float*)d_in[1];
    const float* wq_b = (const float*)d_in[2];
    const float* wk_w = (const float*)d_in[3];
    const float* wk_b = (const float*)d_in[4];
    const float* wv_w = (const float*)d_in[5];
    const float* wv_b = (const float*)d_in[6];
    const float* wo_w = (const float*)d_in[7];
    float* out = (float*)d_out;

    // workspace layout (floats): q[B*S*D] | k[B*S*512] | v[B*S*512] | ctx[B*S*D]
    float* ws = (float*)d_ws;
    float* q  = ws;
    float* k  = q + (size_t)B_ * S_ * D_;
    float* v  = k + (size_t)B_ * S_ * NKV_ * HD_;
    float* cx = v + (size_t)B_ * S_ * NKV_ * HD_;

    const int M = B_ * S_;                       // 8192
    dim3 blk(256);

    // QKV projections
    sgemm_bt<<<dim3(D_/128,         M/128), blk, 0, stream>>>(x, wq_w, wq_b, q, M, D_,        D_);
    sgemm_bt<<<dim3((NKV_*HD_)/128, M/128), blk, 0, stream>>>(x, wk_w, wk_b, k, M, NKV_*HD_,  D_);
    sgemm_bt<<<dim3((NKV_*HD_)/128, M/128), blk, 0, stream>>>(x, wv_w, wv_b, v, M, NKV_*HD_,  D_);

    // RoPE in place (q: 16 heads, k: 4 heads)
    rope_kernel<<<(M * NH_)  / 2, 256, 0, stream>>>(q, NH_);
    rope_kernel<<<(M * NKV_) / 2, 256, 0, stream>>>(k, NKV_);

    // causal GQA flash attention -> ctx [B,S,NH,HD] == [B,S,D]
    flash_attn<<<dim3(S_/32, NH_, B_), 256, 0, stream>>>(q, k, v, cx);

    // output projection (no bias)
    sgemm_bt<<<dim3(D_/128, M/128), blk, 0, stream>>>(cx, wo_w, nullptr, out, M, D_, D_);
}

// Round 2
// 4697.689 us; speedup vs baseline: 1.1139x; 1.1139x over previous
//
#include <hip/hip_runtime.h>
#include <cstdint>
#include <cstddef>

#define B_   4
#define S_   2048
#define D_   2048
#define NH_  16
#define NKV_ 4
#define HD_  128

// ---------------------------------------------------------------------------
// SGEMM: C[M,N] = A[M,K] @ W[N,K]^T + bias   (A row-major, W row-major [N,K])
// 128x128 block tile, BK=16, 256 threads, 8x8 per-thread micro-tile.
// ---------------------------------------------------------------------------
__global__ __launch_bounds__(256) void sgemm_bt(
    const float* __restrict__ A, const float* __restrict__ W,
    const float* __restrict__ bias, float* __restrict__ C,
    int M, int N, int K)
{
    __shared__ float As[16][128];
    __shared__ float Bs[16][128];

    const int tid = threadIdx.x;
    const int tx  = tid & 15;   // col group 0..15
    const int ty  = tid >> 4;   // row group 0..15
    const int bm  = blockIdx.y * 128;
    const int bn  = blockIdx.x * 128;

    const int lr = tid >> 1;        // 0..127 (tile row for loading)
    const int lc = (tid & 1) * 8;   // 0 or 8 (k-col for loading)
    const float* Ap = A + (size_t)(bm + lr) * K + lc;
    const float* Wp = W + (size_t)(bn + lr) * K + lc;

    float acc[8][8];
#pragma unroll
    for (int i = 0; i < 8; ++i)
#pragma unroll
        for (int j = 0; j < 8; ++j) acc[i][j] = 0.f;

    for (int k0 = 0; k0 < K; k0 += 16) {
        float4 a0 = *(const float4*)(Ap + k0);
        float4 a1 = *(const float4*)(Ap + k0 + 4);
        float4 w0 = *(const float4*)(Wp + k0);
        float4 w1 = *(const float4*)(Wp + k0 + 4);

        As[lc+0][lr] = a0.x; As[lc+1][lr] = a0.y; As[lc+2][lr] = a0.z; As[lc+3][lr] = a0.w;
        As[lc+4][lr] = a1.x; As[lc+5][lr] = a1.y; As[lc+6][lr] = a1.z; As[lc+7][lr] = a1.w;
        Bs[lc+0][lr] = w0.x; Bs[lc+1][lr] = w0.y; Bs[lc+2][lr] = w0.z; Bs[lc+3][lr] = w0.w;
        Bs[lc+4][lr] = w1.x; Bs[lc+5][lr] = w1.y; Bs[lc+6][lr] = w1.z; Bs[lc+7][lr] = w1.w;
        __syncthreads();

#pragma unroll
        for (int kk = 0; kk < 16; ++kk) {
            float4 x0 = *(const float4*)&As[kk][ty*8];
            float4 x1 = *(const float4*)&As[kk][ty*8+4];
            float4 y0 = *(const float4*)&Bs[kk][tx*8];
            float4 y1 = *(const float4*)&Bs[kk][tx*8+4];
            float av[8] = {x0.x,x0.y,x0.z,x0.w,x1.x,x1.y,x1.z,x1.w};
            float bv[8] = {y0.x,y0.y,y0.z,y0.w,y1.x,y1.y,y1.z,y1.w};
#pragma unroll
            for (int i = 0; i < 8; ++i)
#pragma unroll
                for (int j = 0; j < 8; ++j)
                    acc[i][j] = fmaf(av[i], bv[j], acc[i][j]);
        }
        __syncthreads();
    }

    float bb[8];
#pragma unroll
    for (int j = 0; j < 8; ++j) bb[j] = bias ? bias[bn + tx*8 + j] : 0.f;

#pragma unroll
    for (int i = 0; i < 8; ++i) {
        float* Cp = C + (size_t)(bm + ty*8 + i) * N + bn + tx*8;
        *(float4*)(Cp)   = make_float4(acc[i][0]+bb[0], acc[i][1]+bb[1],
                                       acc[i][2]+bb[2], acc[i][3]+bb[3]);
        *(float4*)(Cp+4) = make_float4(acc[i][4]+bb[4], acc[i][5]+bb[5],
                                       acc[i][6]+bb[6], acc[i][7]+bb[7]);
    }
}

// ---------------------------------------------------------------------------
// RoPE in place on tensor [B*S, H, 128]. One 128-thread half-block per row.
// ---------------------------------------------------------------------------
__global__ __launch_bounds__(256) void rope_kernel(float* __restrict__ t, int H)
{
    const int tid = threadIdx.x;
    const int rid = blockIdx.x * 2 + (tid >> 7);   // row id in [0, B*S*H)
    const int d   = tid & 127;
    const int s   = (rid / H) & (S_ - 1);          // sequence position
    const int j   = d & 63;

    float inv  = 1.0f / powf(1.0e6f, (float)j * (1.0f / 64.0f));
    float freq = (float)s * inv;
    float sn, cs;
    sincosf(freq, &sn, &cs);

    size_t base = (size_t)rid * HD_;
    float x0 = t[base + d];
    float xp = t[base + (d ^ 64)];
    float rot = (d < 64) ? -xp : xp;
    __syncthreads();                // all reads of this row done before writes
    t[base + d] = fmaf(x0, cs, rot * sn);
}

// ---------------------------------------------------------------------------
// Causal flash attention, GQA. fp32, register softmax + shuffle broadcasts.
// Q: [B,S,NH,HD]  K,V: [B,S,NKV,HD]  ctx: [B,S,NH,HD]
// Block = 256 threads, 32-row Q tile, 32-col K/V tiles.
// Thread (tx=tid&15, ty=(tid>>4)&15) owns S rows {ty, ty+16} x cols {tx, tx+16},
// and O rows {ty, ty+16} x cols {4tx..4tx+3, 64+4tx..64+4tx+3}.
// 16-lane groups (const ty) hold full score rows -> shuffle softmax, no LDS P.
// LDS = Qs 16K + Ks 16.9K + Vs 16K = 49.7 KB -> 3 blocks/CU (12 waves/CU).
// ---------------------------------------------------------------------------
__device__ inline float dot4(float4 a, float4 b, float c) {
    c = fmaf(a.x, b.x, c); c = fmaf(a.y, b.y, c);
    c = fmaf(a.z, b.z, c); return fmaf(a.w, b.w, c);
}

__global__ __launch_bounds__(256) void flash_attn(
    const float* __restrict__ Q, const float* __restrict__ K,
    const float* __restrict__ V, float* __restrict__ ctx)
{
    __shared__ float Qs[32][128];   // reads are 16-lane broadcasts: no pad needed
    __shared__ float Ks[32][132];   // strided row reads: +4 pad
    __shared__ float Vs[32][128];   // lane-consecutive f4 reads: no pad needed

    const int tid = threadIdx.x;
    const int tx  = tid & 15;
    const int ty  = (tid >> 4) & 15;
    const int q0  = blockIdx.x * 32;
    const int h   = blockIdx.y;
    const int b   = blockIdx.z;
    const int kvh = h >> 2;                     // GROUPS = 4
    const float scale = 0.08838834764831845f;   // 1/sqrt(128)

    // ---- stage Q tile, pre-scaled ----
    for (int idx = tid * 4; idx < 32 * 128; idx += 1024) {
        int r = idx >> 7, d = idx & 127;
        float4 qv = *(const float4*)&Q[(((size_t)b * S_ + q0 + r) * NH_ + h) * HD_ + d];
        *(float4*)&Qs[r][d] = make_float4(qv.x*scale, qv.y*scale, qv.z*scale, qv.w*scale);
    }

    float m0 = -3.0e38f, m1 = -3.0e38f;
    float l0 = 0.f, l1 = 0.f;
    float o0[8], o1[8];
#pragma unroll
    for (int c = 0; c < 8; ++c) { o0[c] = 0.f; o1[c] = 0.f; }

    const int ntiles = (q0 >> 5) + 1;
    for (int t = 0; t < ntiles; ++t) {
        const int k0 = t * 32;
        __syncthreads();    // prev tile's Vs reads done (and Qs stores, t=0)

        // ---- stage K/V tile ----
        for (int idx = tid * 4; idx < 32 * 128; idx += 1024) {
            int r = idx >> 7, d = idx & 127;
            size_t g = (((size_t)b * S_ + k0 + r) * NKV_ + kvh) * HD_ + d;
            *(float4*)&Ks[r][d] = *(const float4*)&K[g];
            *(float4*)&Vs[r][d] = *(const float4*)&V[g];
        }
        __syncthreads();

        // ---- S = Qs . Ks^T : 2x2 micro-tile per thread ----
        float a00 = 0.f, a01 = 0.f, a10 = 0.f, a11 = 0.f;
#pragma unroll 4
        for (int d = 0; d < 128; d += 4) {
            float4 qa = *(const float4*)&Qs[ty][d];
            float4 qb = *(const float4*)&Qs[ty + 16][d];
            float4 ka = *(const float4*)&Ks[tx][d];
            float4 kb = *(const float4*)&Ks[tx + 16][d];
            a00 = dot4(qa, ka, a00); a01 = dot4(qa, kb, a01);
            a10 = dot4(qb, ka, a10); a11 = dot4(qb, kb, a11);
        }

        // ---- causal mask (only the diagonal tile can mask) ----
        if (t == ntiles - 1) {
            int r0 = q0 + ty, r1 = q0 + ty + 16;
            int c0 = k0 + tx, c1 = k0 + tx + 16;
            if (c0 > r0) a00 = -3.0e38f;
            if (c1 > r0) a01 = -3.0e38f;
            if (c0 > r1) a10 = -3.0e38f;
            if (c1 > r1) a11 = -3.0e38f;
        }

        // ---- register softmax over the 16-lane row group ----
        float rm0 = fmaxf(a00, a01), rm1 = fmaxf(a10, a11);
#pragma unroll
        for (int msk = 1; msk < 16; msk <<= 1) {
            rm0 = fmaxf(rm0, __shfl_xor(rm0, msk, 16));
            rm1 = fmaxf(rm1, __shfl_xor(rm1, msk, 16));
        }
        float m0n = fmaxf(m0, rm0), m1n = fmaxf(m1, rm1);
        float al0 = __expf(m0 - m0n), al1 = __expf(m1 - m1n);
        float p00 = __expf(a00 - m0n), p01 = __expf(a01 - m0n);
        float p10 = __expf(a10 - m1n), p11 = __expf(a11 - m1n);
        float s0 = p00 + p01, s1 = p10 + p11;
#pragma unroll
        for (int msk = 1; msk < 16; msk <<= 1) {
            s0 += __shfl_xor(s0, msk, 16);
            s1 += __shfl_xor(s1, msk, 16);
        }
        l0 = l0 * al0 + s0;
        l1 = l1 * al1 + s1;
        m0 = m0n; m1 = m1n;
#pragma unroll
        for (int c = 0; c < 8; ++c) { o0[c] *= al0; o1[c] *= al1; }

        // ---- O += P.V : broadcast P from owning lane, read V from LDS ----
#pragma unroll 4
        for (int jj = 0; jj < 16; ++jj) {
            float pa0 = __shfl(p00, jj, 16);    // P[ty   ][k0+jj]
            float pb0 = __shfl(p01, jj, 16);    // P[ty   ][k0+jj+16]
            float pa1 = __shfl(p10, jj, 16);    // P[ty+16][k0+jj]
            float pb1 = __shfl(p11, jj, 16);    // P[ty+16][k0+jj+16]
            float4 va_lo = *(const float4*)&Vs[jj][tx * 4];
            float4 va_hi = *(const float4*)&Vs[jj][64 + tx * 4];
            float4 vb_lo = *(const float4*)&Vs[jj + 16][tx * 4];
            float4 vb_hi = *(const float4*)&Vs[jj + 16][64 + tx * 4];

            o0[0] = fmaf(pa0, va_lo.x, o0[0]); o0[1] = fmaf(pa0, va_lo.y, o0[1]);
            o0[2] = fmaf(pa0, va_lo.z, o0[2]); o0[3] = fmaf(pa0, va_lo.w, o0[3]);
            o0[4] = fmaf(pa0, va_hi.x, o0[4]); o0[5] = fmaf(pa0, va_hi.y, o0[5]);
            o0[6] = fmaf(pa0, va_hi.z, o0[6]); o0[7] = fmaf(pa0, va_hi.w, o0[7]);

            o0[0] = fmaf(pb0, vb_lo.x, o0[0]); o0[1] = fmaf(pb0, vb_lo.y, o0[1]);
            o0[2] = fmaf(pb0, vb_lo.z, o0[2]); o0[3] = fmaf(pb0, vb_lo.w, o0[3]);
            o0[4] = fmaf(pb0, vb_hi.x, o0[4]); o0[5] = fmaf(pb0, vb_hi.y, o0[5]);
            o0[6] = fmaf(pb0, vb_hi.z, o0[6]); o0[7] = fmaf(pb0, vb_hi.w, o0[7]);

            o1[0] = fmaf(pa1, va_lo.x, o1[0]); o1[1] = fmaf(pa1, va_lo.y, o1[1]);
            o1[2] = fmaf(pa1, va_lo.z, o1[2]); o1[3] = fmaf(pa1, va_lo.w, o1[3]);
            o1[4] = fmaf(pa1, va_hi.x, o1[4]); o1[5] = fmaf(pa1, va_hi.y, o1[5]);
            o1[6] = fmaf(pa1, va_hi.z, o1[6]); o1[7] = fmaf(pa1, va_hi.w, o1[7]);

            o1[0] = fmaf(pb1, vb_lo.x, o1[0]); o1[1] = fmaf(pb1, vb_lo.y, o1[1]);
            o1[2] = fmaf(pb1, vb_lo.z, o1[2]); o1[3] = fmaf(pb1, vb_lo.w, o1[3]);
            o1[4] = fmaf(pb1, vb_hi.x, o1[4]); o1[5] = fmaf(pb1, vb_hi.y, o1[5]);
            o1[6] = fmaf(pb1, vb_hi.z, o1[6]); o1[7] = fmaf(pb1, vb_hi.w, o1[7]);
        }
    }

    // ---- epilogue ----
    float il0 = 1.0f / l0, il1 = 1.0f / l1;
    float* c0p = &ctx[(((size_t)b * S_ + q0 + ty)      * NH_ + h) * HD_];
    float* c1p = &ctx[(((size_t)b * S_ + q0 + ty + 16) * NH_ + h) * HD_];
    *(float4*)(c0p + 4*tx)      = make_float4(o0[0]*il0, o0[1]*il0, o0[2]*il0, o0[3]*il0);
    *(float4*)(c0p + 64 + 4*tx) = make_float4(o0[4]*il0, o0[5]*il0, o0[6]*il0, o0[7]*il0);
    *(float4*)(c1p + 4*tx)      = make_float4(o1[0]*il1, o1[1]*il1, o1[2]*il1, o1[3]*il1);
    *(float4*)(c1p + 64 + 4*tx) = make_float4(o1[4]*il1, o1[5]*il1, o1[6]*il1, o1[7]*il1);
}

// ---------------------------------------------------------------------------
extern "C" void kernel_launch(void* const* d_in, const int* in_sizes, int n_in,
                              void* d_out, int out_size, void* d_ws, size_t ws_size,
                              hipStream_t stream)
{
    const float* x    = (const float*)d_in[0];
    const float* wq_w = (const float*)d_in[1];
    const float* wq_b = (const float*)d_in[2];
    const float* wk_w = (const float*)d_in[3];
    const float* wk_b = (const float*)d_in[4];
    const float* wv_w = (const float*)d_in[5];
    const float* wv_b = (const float*)d_in[6];
    const float* wo_w = (const float*)d_in[7];
    float* out = (float*)d_out;

    float* ws = (float*)d_ws;
    float* q  = ws;
    float* k  = q + (size_t)B_ * S_ * D_;
    float* v  = k + (size_t)B_ * S_ * NKV_ * HD_;
    float* cx = v + (size_t)B_ * S_ * NKV_ * HD_;

    const int M = B_ * S_;                       // 8192
    dim3 blk(256);

    sgemm_bt<<<dim3(D_/128,         M/128), blk, 0, stream>>>(x, wq_w, wq_b, q, M, D_,       D_);
    sgemm_bt<<<dim3((NKV_*HD_)/128, M/128), blk, 0, stream>>>(x, wk_w, wk_b, k, M, NKV_*HD_, D_);
    sgemm_bt<<<dim3((NKV_*HD_)/128, M/128), blk, 0, stream>>>(x, wv_w, wv_b, v, M, NKV_*HD_, D_);

    rope_kernel<<<(M * NH_)  / 2, 256, 0, stream>>>(q, NH_);
    rope_kernel<<<(M * NKV_) / 2, 256, 0, stream>>>(k, NKV_);

    flash_attn<<<dim3(S_/32, NH_, B_), 256, 0, stream>>>(q, k, v, cx);

    sgemm_bt<<<dim3(D_/128, M/128), blk, 0, stream>>>(cx, wo_w, nullptr, out, M, D_, D_);
}

// Round 3
// 2923.175 us; speedup vs baseline: 1.7901x; 1.6071x over previous
//
#include <hip/hip_runtime.h>
#include <cstdint>
#include <cstddef>

#define B_   4
#define S_   2048
#define D_   2048
#define NH_  16
#define NKV_ 4
#define HD_  128

typedef __attribute__((ext_vector_type(8))) short short8;
typedef __attribute__((ext_vector_type(4))) float f32x4;

// ---------------------------------------------------------------------------
// fp32 -> (bf16_hi, bf16_lo) split helpers (RNE)
// ---------------------------------------------------------------------------
__device__ __forceinline__ unsigned short f2bf(float f) {
    union { float f; unsigned u; } v{f};
    unsigned r = v.u + 0x7FFF + ((v.u >> 16) & 1);
    return (unsigned short)(r >> 16);
}
__device__ __forceinline__ float bf2f(unsigned short h) {
    union { unsigned u; float f; } v{(unsigned)h << 16};
    return v.f;
}
__device__ __forceinline__ void split1(float f, unsigned short& h, unsigned short& l) {
    h = f2bf(f);
    l = f2bf(f - bf2f(h));
}

// src fp32 [n] -> hi/lo bf16 [n]. n must be a multiple of 1024.
__global__ __launch_bounds__(256) void split_bf16_k(
    const float* __restrict__ src, ushort* __restrict__ hi, ushort* __restrict__ lo)
{
    size_t i = ((size_t)blockIdx.x * 256 + threadIdx.x) * 4;
    float4 f = *(const float4*)&src[i];
    ushort4 h, l;
    split1(f.x, h.x, l.x); split1(f.y, h.y, l.y);
    split1(f.z, h.z, l.z); split1(f.w, h.w, l.w);
    *(ushort4*)&hi[i] = h;
    *(ushort4*)&lo[i] = l;
}

// ---------------------------------------------------------------------------
// Split-bf16 MFMA GEMM: C[M,N] = (Ah+Al)[M,K] @ (Bh+Bl)[N,K]^T + bias
// (drops lo*lo). 128x128 tile, BK=32, 4 waves, each wave a 64x64 quadrant as
// 4x4 grid of 16x16x32 MFMA tiles. global_load_lds width=16. LDS 32 KB.
// ---------------------------------------------------------------------------
__global__ __launch_bounds__(256) void gemm_mfma_split(
    const ushort* __restrict__ Ah, const ushort* __restrict__ Al,
    const ushort* __restrict__ Bh, const ushort* __restrict__ Bl,
    const float* __restrict__ bias, float* __restrict__ C,
    int M, int N, int K)
{
    __shared__ ushort sA[2][128 * 32];   // [0]=hi [1]=lo, row-major [128][32]
    __shared__ ushort sB[2][128 * 32];

    const int tid  = threadIdx.x;
    const int wave = tid >> 6;
    const int lane = tid & 63;
    const int bm = blockIdx.y * 128;
    const int bn = blockIdx.x * 128;
    const int wm = (wave & 1) * 64;
    const int wn = (wave >> 1) * 64;

    f32x4 acc[4][4];
#pragma unroll
    for (int mt = 0; mt < 4; ++mt)
#pragma unroll
        for (int nt = 0; nt < 4; ++nt) acc[mt][nt] = 0.f;

    // staging: wave w owns one buffer (8 KB = 8 wave-ops of 1 KB each)
    const ushort* gbase = (wave == 0) ? Ah : (wave == 1) ? Al : (wave == 2) ? Bh : Bl;
    ushort* sbase = (wave == 0) ? sA[0] : (wave == 1) ? sA[1] : (wave == 2) ? sB[0] : sB[1];
    const int rb   = (wave < 2) ? bm : bn;
    const int lrow = lane >> 2;          // 0..15
    const int lcol = (lane & 3) * 8;     // bf16-element offset in row

    const int koff = (lane >> 4) * 8;
    const int rsel = lane & 15;

    for (int k0 = 0; k0 < K; k0 += 32) {
        __syncthreads();                 // prior ds_reads done before overwrite
        const ushort* g0 = gbase + (size_t)(rb + lrow) * K + k0 + lcol;
#pragma unroll
        for (int i = 0; i < 8; ++i) {
            __builtin_amdgcn_global_load_lds(
                (const __attribute__((address_space(1))) unsigned int*)(g0 + (size_t)i * 16 * K),
                (__attribute__((address_space(3))) unsigned int*)(sbase + i * 512),
                16, 0, 0);
        }
        __syncthreads();                 // drains vmcnt

        short8 a_h[4], a_l[4], b_h[4], b_l[4];
#pragma unroll
        for (int t = 0; t < 4; ++t) {
            a_h[t] = *(const short8*)&sA[0][(wm + t * 16 + rsel) * 32 + koff];
            a_l[t] = *(const short8*)&sA[1][(wm + t * 16 + rsel) * 32 + koff];
            b_h[t] = *(const short8*)&sB[0][(wn + t * 16 + rsel) * 32 + koff];
            b_l[t] = *(const short8*)&sB[1][(wn + t * 16 + rsel) * 32 + koff];
        }
#pragma unroll
        for (int mt = 0; mt < 4; ++mt)
#pragma unroll
            for (int nt = 0; nt < 4; ++nt) {
                acc[mt][nt] = __builtin_amdgcn_mfma_f32_16x16x32_bf16(a_h[mt], b_h[nt], acc[mt][nt], 0, 0, 0);
                acc[mt][nt] = __builtin_amdgcn_mfma_f32_16x16x32_bf16(a_h[mt], b_l[nt], acc[mt][nt], 0, 0, 0);
                acc[mt][nt] = __builtin_amdgcn_mfma_f32_16x16x32_bf16(a_l[mt], b_h[nt], acc[mt][nt], 0, 0, 0);
            }
    }

    // epilogue: C/D layout col=lane&15, row=(lane>>4)*4+reg
    const int crow0 = bm + wm + (lane >> 4) * 4;
    const int ccol0 = bn + wn + (lane & 15);
#pragma unroll
    for (int nt = 0; nt < 4; ++nt) {
        float bb = bias ? bias[ccol0 + nt * 16] : 0.f;
#pragma unroll
        for (int mt = 0; mt < 4; ++mt)
#pragma unroll
            for (int r = 0; r < 4; ++r)
                C[(size_t)(crow0 + mt * 16 + r) * N + ccol0 + nt * 16] = acc[mt][nt][r] + bb;
    }
}

// ---------------------------------------------------------------------------
// RoPE in place on tensor [B*S, H, 128]. One 128-thread half-block per row.
// ---------------------------------------------------------------------------
__global__ __launch_bounds__(256) void rope_kernel(float* __restrict__ t, int H)
{
    const int tid = threadIdx.x;
    const int rid = blockIdx.x * 2 + (tid >> 7);
    const int d   = tid & 127;
    const int s   = (rid / H) & (S_ - 1);
    const int j   = d & 63;

    float inv  = 1.0f / powf(1.0e6f, (float)j * (1.0f / 64.0f));
    float freq = (float)s * inv;
    float sn, cs;
    sincosf(freq, &sn, &cs);

    size_t base = (size_t)rid * HD_;
    float x0 = t[base + d];
    float xp = t[base + (d ^ 64)];
    float rot = (d < 64) ? -xp : xp;
    __syncthreads();
    t[base + d] = fmaf(x0, cs, rot * sn);
}

// ---------------------------------------------------------------------------
// Causal flash attention, GQA. fp32 compute; writes bf16 hi/lo ctx directly.
// Heaviest q-tiles dispatched first (reversed blockIdx.x) for load balance.
// ---------------------------------------------------------------------------
__device__ __forceinline__ float dot4(float4 a, float4 b, float c) {
    c = fmaf(a.x, b.x, c); c = fmaf(a.y, b.y, c);
    c = fmaf(a.z, b.z, c); return fmaf(a.w, b.w, c);
}

__global__ __launch_bounds__(256) void flash_attn(
    const float* __restrict__ Q, const float* __restrict__ K,
    const float* __restrict__ V, ushort* __restrict__ ctx_hi,
    ushort* __restrict__ ctx_lo)
{
    __shared__ float Qs[32][132];   // +4 pad: rows land on different banks
    __shared__ float Ks[32][132];
    __shared__ float Vs[32][128];   // lane-consecutive f4 reads: no pad needed

    const int tid = threadIdx.x;
    const int tx  = tid & 15;
    const int ty  = (tid >> 4) & 15;
    const int q0  = (gridDim.x - 1 - blockIdx.x) * 32;   // heavy tiles first
    const int h   = blockIdx.y;
    const int b   = blockIdx.z;
    const int kvh = h >> 2;
    const float scale = 0.08838834764831845f;   // 1/sqrt(128)

    for (int idx = tid * 4; idx < 32 * 128; idx += 1024) {
        int r = idx >> 7, d = idx & 127;
        float4 qv = *(const float4*)&Q[(((size_t)b * S_ + q0 + r) * NH_ + h) * HD_ + d];
        *(float4*)&Qs[r][d] = make_float4(qv.x*scale, qv.y*scale, qv.z*scale, qv.w*scale);
    }

    float m0 = -3.0e38f, m1 = -3.0e38f;
    float l0 = 0.f, l1 = 0.f;
    float o0[8], o1[8];
#pragma unroll
    for (int c = 0; c < 8; ++c) { o0[c] = 0.f; o1[c] = 0.f; }

    const int ntiles = (q0 >> 5) + 1;
    for (int t = 0; t < ntiles; ++t) {
        const int k0 = t * 32;
        __syncthreads();

        for (int idx = tid * 4; idx < 32 * 128; idx += 1024) {
            int r = idx >> 7, d = idx & 127;
            size_t g = (((size_t)b * S_ + k0 + r) * NKV_ + kvh) * HD_ + d;
            *(float4*)&Ks[r][d] = *(const float4*)&K[g];
            *(float4*)&Vs[r][d] = *(const float4*)&V[g];
        }
        __syncthreads();

        float a00 = 0.f, a01 = 0.f, a10 = 0.f, a11 = 0.f;
#pragma unroll 8
        for (int d = 0; d < 128; d += 4) {
            float4 qa = *(const float4*)&Qs[ty][d];
            float4 qb = *(const float4*)&Qs[ty + 16][d];
            float4 ka = *(const float4*)&Ks[tx][d];
            float4 kb = *(const float4*)&Ks[tx + 16][d];
            a00 = dot4(qa, ka, a00); a01 = dot4(qa, kb, a01);
            a10 = dot4(qb, ka, a10); a11 = dot4(qb, kb, a11);
        }

        if (t == ntiles - 1) {
            int r0 = q0 + ty, r1 = q0 + ty + 16;
            int c0 = k0 + tx, c1 = k0 + tx + 16;
            if (c0 > r0) a00 = -3.0e38f;
            if (c1 > r0) a01 = -3.0e38f;
            if (c0 > r1) a10 = -3.0e38f;
            if (c1 > r1) a11 = -3.0e38f;
        }

        float rm0 = fmaxf(a00, a01), rm1 = fmaxf(a10, a11);
#pragma unroll
        for (int msk = 1; msk < 16; msk <<= 1) {
            rm0 = fmaxf(rm0, __shfl_xor(rm0, msk, 16));
            rm1 = fmaxf(rm1, __shfl_xor(rm1, msk, 16));
        }
        float m0n = fmaxf(m0, rm0), m1n = fmaxf(m1, rm1);
        float al0 = __expf(m0 - m0n), al1 = __expf(m1 - m1n);
        float p00 = __expf(a00 - m0n), p01 = __expf(a01 - m0n);
        float p10 = __expf(a10 - m1n), p11 = __expf(a11 - m1n);
        float s0 = p00 + p01, s1 = p10 + p11;
#pragma unroll
        for (int msk = 1; msk < 16; msk <<= 1) {
            s0 += __shfl_xor(s0, msk, 16);
            s1 += __shfl_xor(s1, msk, 16);
        }
        l0 = l0 * al0 + s0;
        l1 = l1 * al1 + s1;
        m0 = m0n; m1 = m1n;
#pragma unroll
        for (int c = 0; c < 8; ++c) { o0[c] *= al0; o1[c] *= al1; }

#pragma unroll 4
        for (int jj = 0; jj < 16; ++jj) {
            float pa0 = __shfl(p00, jj, 16);
            float pb0 = __shfl(p01, jj, 16);
            float pa1 = __shfl(p10, jj, 16);
            float pb1 = __shfl(p11, jj, 16);
            float4 va_lo = *(const float4*)&Vs[jj][tx * 4];
            float4 va_hi = *(const float4*)&Vs[jj][64 + tx * 4];
            float4 vb_lo = *(const float4*)&Vs[jj + 16][tx * 4];
            float4 vb_hi = *(const float4*)&Vs[jj + 16][64 + tx * 4];

            o0[0] = fmaf(pa0, va_lo.x, o0[0]); o0[1] = fmaf(pa0, va_lo.y, o0[1]);
            o0[2] = fmaf(pa0, va_lo.z, o0[2]); o0[3] = fmaf(pa0, va_lo.w, o0[3]);
            o0[4] = fmaf(pa0, va_hi.x, o0[4]); o0[5] = fmaf(pa0, va_hi.y, o0[5]);
            o0[6] = fmaf(pa0, va_hi.z, o0[6]); o0[7] = fmaf(pa0, va_hi.w, o0[7]);

            o0[0] = fmaf(pb0, vb_lo.x, o0[0]); o0[1] = fmaf(pb0, vb_lo.y, o0[1]);
            o0[2] = fmaf(pb0, vb_lo.z, o0[2]); o0[3] = fmaf(pb0, vb_lo.w, o0[3]);
            o0[4] = fmaf(pb0, vb_hi.x, o0[4]); o0[5] = fmaf(pb0, vb_hi.y, o0[5]);
            o0[6] = fmaf(pb0, vb_hi.z, o0[6]); o0[7] = fmaf(pb0, vb_hi.w, o0[7]);

            o1[0] = fmaf(pa1, va_lo.x, o1[0]); o1[1] = fmaf(pa1, va_lo.y, o1[1]);
            o1[2] = fmaf(pa1, va_lo.z, o1[2]); o1[3] = fmaf(pa1, va_lo.w, o1[3]);
            o1[4] = fmaf(pa1, va_hi.x, o1[4]); o1[5] = fmaf(pa1, va_hi.y, o1[5]);
            o1[6] = fmaf(pa1, va_hi.z, o1[6]); o1[7] = fmaf(pa1, va_hi.w, o1[7]);

            o1[0] = fmaf(pb1, vb_lo.x, o1[0]); o1[1] = fmaf(pb1, vb_lo.y, o1[1]);
            o1[2] = fmaf(pb1, vb_lo.z, o1[2]); o1[3] = fmaf(pb1, vb_lo.w, o1[3]);
            o1[4] = fmaf(pb1, vb_hi.x, o1[4]); o1[5] = fmaf(pb1, vb_hi.y, o1[5]);
            o1[6] = fmaf(pb1, vb_hi.z, o1[6]); o1[7] = fmaf(pb1, vb_hi.w, o1[7]);
        }
    }

    // epilogue: normalize, split to bf16 hi/lo, store [B,S,NH,HD]
    float il0 = 1.0f / l0, il1 = 1.0f / l1;
    size_t base0 = (((size_t)b * S_ + q0 + ty)      * NH_ + h) * (size_t)HD_;
    size_t base1 = (((size_t)b * S_ + q0 + ty + 16) * NH_ + h) * (size_t)HD_;

    ushort4 hh, ll;
    split1(o0[0]*il0, hh.x, ll.x); split1(o0[1]*il0, hh.y, ll.y);
    split1(o0[2]*il0, hh.z, ll.z); split1(o0[3]*il0, hh.w, ll.w);
    *(ushort4*)&ctx_hi[base0 + 4*tx] = hh; *(ushort4*)&ctx_lo[base0 + 4*tx] = ll;
    split1(o0[4]*il0, hh.x, ll.x); split1(o0[5]*il0, hh.y, ll.y);
    split1(o0[6]*il0, hh.z, ll.z); split1(o0[7]*il0, hh.w, ll.w);
    *(ushort4*)&ctx_hi[base0 + 64 + 4*tx] = hh; *(ushort4*)&ctx_lo[base0 + 64 + 4*tx] = ll;
    split1(o1[0]*il1, hh.x, ll.x); split1(o1[1]*il1, hh.y, ll.y);
    split1(o1[2]*il1, hh.z, ll.z); split1(o1[3]*il1, hh.w, ll.w);
    *(ushort4*)&ctx_hi[base1 + 4*tx] = hh; *(ushort4*)&ctx_lo[base1 + 4*tx] = ll;
    split1(o1[4]*il1, hh.x, ll.x); split1(o1[5]*il1, hh.y, ll.y);
    split1(o1[6]*il1, hh.z, ll.z); split1(o1[7]*il1, hh.w, ll.w);
    *(ushort4*)&ctx_hi[base1 + 64 + 4*tx] = hh; *(ushort4*)&ctx_lo[base1 + 64 + 4*tx] = ll;
}

// ---------------------------------------------------------------------------
extern "C" void kernel_launch(void* const* d_in, const int* in_sizes, int n_in,
                              void* d_out, int out_size, void* d_ws, size_t ws_size,
                              hipStream_t stream)
{
    const float* x    = (const float*)d_in[0];
    const float* wq_w = (const float*)d_in[1];
    const float* wq_b = (const float*)d_in[2];
    const float* wk_w = (const float*)d_in[3];
    const float* wk_b = (const float*)d_in[4];
    const float* wv_w = (const float*)d_in[5];
    const float* wv_b = (const float*)d_in[6];
    const float* wo_w = (const float*)d_in[7];
    float* out = (float*)d_out;

    const int M = B_ * S_;                        // 8192
    const size_t NX   = (size_t)M * D_;           // 16,777,216
    const size_t NKVE = (size_t)M * NKV_ * HD_;   // 4,194,304
    const size_t NWQ  = (size_t)D_ * D_;          // 4,194,304
    const size_t NWK  = (size_t)(NKV_ * HD_) * D_;// 1,048,576

    // workspace layout (~210 MB total)
    float*  q   = (float*)d_ws;
    float*  k   = q + NX;
    float*  v   = k + NKVE;
    ushort* xh  = (ushort*)(v + NKVE);   // later reused as ctx_hi
    ushort* xl  = xh + NX;               // later reused as ctx_lo
    ushort* wqh = xl + NX;
    ushort* wql = wqh + NWQ;
    ushort* wkh = wql + NWQ;
    ushort* wkl = wkh + NWK;
    ushort* wvh = wkl + NWK;
    ushort* wvl = wvh + NWK;
    ushort* woh = wvl + NWK;
    ushort* wol = woh + NWQ;

    // 1) fp32 -> bf16 hi/lo splits
    split_bf16_k<<<NX  / 1024, 256, 0, stream>>>(x,    xh,  xl);
    split_bf16_k<<<NWQ / 1024, 256, 0, stream>>>(wq_w, wqh, wql);
    split_bf16_k<<<NWK / 1024, 256, 0, stream>>>(wk_w, wkh, wkl);
    split_bf16_k<<<NWK / 1024, 256, 0, stream>>>(wv_w, wvh, wvl);
    split_bf16_k<<<NWQ / 1024, 256, 0, stream>>>(wo_w, woh, wol);

    // 2) QKV projections (MFMA split-bf16)
    gemm_mfma_split<<<dim3(D_/128,         M/128), 256, 0, stream>>>(xh, xl, wqh, wql, wq_b, q, M, D_,       D_);
    gemm_mfma_split<<<dim3((NKV_*HD_)/128, M/128), 256, 0, stream>>>(xh, xl, wkh, wkl, wk_b, k, M, NKV_*HD_, D_);
    gemm_mfma_split<<<dim3((NKV_*HD_)/128, M/128), 256, 0, stream>>>(xh, xl, wvh, wvl, wv_b, v, M, NKV_*HD_, D_);

    // 3) RoPE
    rope_kernel<<<(M * NH_)  / 2, 256, 0, stream>>>(q, NH_);
    rope_kernel<<<(M * NKV_) / 2, 256, 0, stream>>>(k, NKV_);

    // 4) attention -> ctx hi/lo (reuses x-split buffers; x splits dead by now)
    flash_attn<<<dim3(S_/32, NH_, B_), 256, 0, stream>>>(q, k, v, xh, xl);

    // 5) output projection
    gemm_mfma_split<<<dim3(D_/128, M/128), 256, 0, stream>>>(xh, xl, woh, wol, nullptr, out, M, D_, D_);
}

// Round 5
// 1314.841 us; speedup vs baseline: 3.9798x; 2.2232x over previous
//
#include <hip/hip_runtime.h>
#include <cstdint>
#include <cstddef>

#define B_   4
#define S_   2048
#define D_   2048
#define NH_  16
#define NKV_ 4
#define HD_  128

typedef __attribute__((ext_vector_type(8))) short short8;
typedef __attribute__((ext_vector_type(4))) float f32x4;

// ---------------------------------------------------------------------------
// fp32 -> (bf16_hi, bf16_lo) split helpers (RNE)
// ---------------------------------------------------------------------------
__device__ __forceinline__ unsigned short f2bf(float f) {
    union { float f; unsigned u; } v{f};
    unsigned r = v.u + 0x7FFF + ((v.u >> 16) & 1);
    return (unsigned short)(r >> 16);
}
__device__ __forceinline__ float bf2f(unsigned short h) {
    union { unsigned u; float f; } v{(unsigned)h << 16};
    return v.f;
}
__device__ __forceinline__ void split1(float f, unsigned short& h, unsigned short& l) {
    h = f2bf(f);
    l = f2bf(f - bf2f(h));
}
__device__ __forceinline__ unsigned pack_split(float f) {
    unsigned short h, l; split1(f, h, l);
    return (unsigned)h | ((unsigned)l << 16);
}
// 8 packed u32 (hi|lo<<16) -> two bf16x8 fragments
__device__ __forceinline__ void unpack8(const unsigned* w, short8& hi, short8& lo) {
    unsigned h[4], l[4];
#pragma unroll
    for (int i = 0; i < 4; ++i) {
        h[i] = (w[2*i] & 0xFFFFu) | (w[2*i+1] << 16);
        l[i] = (w[2*i] >> 16) | (w[2*i+1] & 0xFFFF0000u);
    }
    hi = *(short8*)h; lo = *(short8*)l;
}

// src fp32 [n] -> hi/lo bf16 [n]. n must be a multiple of 1024.
__global__ __launch_bounds__(256) void split_bf16_k(
    const float* __restrict__ src, ushort* __restrict__ hi, ushort* __restrict__ lo)
{
    size_t i = ((size_t)blockIdx.x * 256 + threadIdx.x) * 4;
    float4 f = *(const float4*)&src[i];
    ushort4 h, l;
    split1(f.x, h.x, l.x); split1(f.y, h.y, l.y);
    split1(f.z, h.z, l.z); split1(f.w, h.w, l.w);
    *(ushort4*)&hi[i] = h;
    *(ushort4*)&lo[i] = l;
}

// ---------------------------------------------------------------------------
// Split-bf16 MFMA GEMM (round-3 verified form):
// C[M,N] = (Ah+Al)[M,K] @ (Bh+Bl)[N,K]^T + bias  (drops lo*lo)
// ---------------------------------------------------------------------------
__global__ __launch_bounds__(256) void gemm_mfma_split(
    const ushort* __restrict__ Ah, const ushort* __restrict__ Al,
    const ushort* __restrict__ Bh, const ushort* __restrict__ Bl,
    const float* __restrict__ bias, float* __restrict__ C,
    int M, int N, int K)
{
    __shared__ ushort sA[2][128 * 32];   // [0]=hi [1]=lo, row-major [128][32]
    __shared__ ushort sB[2][128 * 32];

    const int tid  = threadIdx.x;
    const int wave = tid >> 6;
    const int lane = tid & 63;
    const int bm = blockIdx.y * 128;
    const int bn = blockIdx.x * 128;
    const int wm = (wave & 1) * 64;
    const int wn = (wave >> 1) * 64;

    f32x4 acc[4][4];
#pragma unroll
    for (int mt = 0; mt < 4; ++mt)
#pragma unroll
        for (int nt = 0; nt < 4; ++nt) acc[mt][nt] = 0.f;

    const ushort* gbase = (wave == 0) ? Ah : (wave == 1) ? Al : (wave == 2) ? Bh : Bl;
    ushort* sbase = (wave == 0) ? sA[0] : (wave == 1) ? sA[1] : (wave == 2) ? sB[0] : sB[1];
    const int rb   = (wave < 2) ? bm : bn;
    const int lrow = lane >> 2;          // 0..15
    const int lcol = (lane & 3) * 8;     // element offset in k

    const int koff = (lane >> 4) * 8;
    const int rsel = lane & 15;

    for (int k0 = 0; k0 < K; k0 += 32) {
        __syncthreads();
        const ushort* g0 = gbase + (size_t)(rb + lrow) * K + k0 + lcol;
#pragma unroll
        for (int i = 0; i < 8; ++i) {
            __builtin_amdgcn_global_load_lds(
                (const __attribute__((address_space(1))) unsigned int*)(g0 + (size_t)i * 16 * K),
                (__attribute__((address_space(3))) unsigned int*)(sbase + i * 512),
                16, 0, 0);
        }
        __syncthreads();

        short8 a_h[4], a_l[4], b_h[4], b_l[4];
#pragma unroll
        for (int t = 0; t < 4; ++t) {
            a_h[t] = *(const short8*)&sA[0][(wm + t * 16 + rsel) * 32 + koff];
            a_l[t] = *(const short8*)&sA[1][(wm + t * 16 + rsel) * 32 + koff];
            b_h[t] = *(const short8*)&sB[0][(wn + t * 16 + rsel) * 32 + koff];
            b_l[t] = *(const short8*)&sB[1][(wn + t * 16 + rsel) * 32 + koff];
        }
#pragma unroll
        for (int mt = 0; mt < 4; ++mt)
#pragma unroll
            for (int nt = 0; nt < 4; ++nt) {
                acc[mt][nt] = __builtin_amdgcn_mfma_f32_16x16x32_bf16(a_h[mt], b_h[nt], acc[mt][nt], 0, 0, 0);
                acc[mt][nt] = __builtin_amdgcn_mfma_f32_16x16x32_bf16(a_h[mt], b_l[nt], acc[mt][nt], 0, 0, 0);
                acc[mt][nt] = __builtin_amdgcn_mfma_f32_16x16x32_bf16(a_l[mt], b_h[nt], acc[mt][nt], 0, 0, 0);
            }
    }

    const int crow0 = bm + wm + (lane >> 4) * 4;
    const int ccol0 = bn + wn + (lane & 15);
#pragma unroll
    for (int nt = 0; nt < 4; ++nt) {
        float bb = bias ? bias[ccol0 + nt * 16] : 0.f;
#pragma unroll
        for (int mt = 0; mt < 4; ++mt)
#pragma unroll
            for (int r = 0; r < 4; ++r)
                C[(size_t)(crow0 + mt * 16 + r) * N + ccol0 + nt * 16] = acc[mt][nt][r] + bb;
    }
}

// ---------------------------------------------------------------------------
// In-place RoPE (+scale) and fp32 -> interleaved hi/lo bf16 split.
// Row r of 128 fp32 becomes 128 hi ushorts | 128 lo ushorts (same 512 bytes).
// ---------------------------------------------------------------------------
__global__ __launch_bounds__(256) void rope_split_kernel(
    float* __restrict__ t, int H, float scale, int do_rope)
{
    const int tid = threadIdx.x;
    const int rid = blockIdx.x * 2 + (tid >> 7);
    const int d   = tid & 127;
    size_t fbase = (size_t)rid * 128;
    float val;
    if (do_rope) {
        const int s = (rid / H) & (S_ - 1);
        const int j = d & 63;
        float inv  = 1.0f / powf(1.0e6f, (float)j * (1.0f / 64.0f));
        float fr = (float)s * inv;
        float sn, cs; sincosf(fr, &sn, &cs);
        float x0 = t[fbase + d];
        float xp = t[fbase + (d ^ 64)];
        float rot = (d < 64) ? -xp : xp;
        val = fmaf(x0, cs, rot * sn) * scale;
    } else {
        val = t[fbase + d] * scale;
    }
    __syncthreads();               // all fp32 reads of these 2 rows done
    unsigned short h, l; split1(val, h, l);
    ushort* us = (ushort*)t;
    us[(size_t)rid * 256 + d]       = h;
    us[(size_t)rid * 256 + 128 + d] = l;
}

// ---------------------------------------------------------------------------
// MFMA causal flash attention, GQA, split-bf16 precision.
// Qsp: interleaved hi/lo Q rows [B,S,NH]x(128h|128l) (read-only here).
// Ksp/Vsp: interleaved hi/lo K/V rows [B,S,NKV]x(128h|128l).
// ctx_h/ctx_l: PLANAR outputs, [B*S][2048] ushorts, feature = h*128+d.
// Block: 4 waves x 32 q-rows (BM=128); KV tile BN=32.
// All waves execute all tiles (fully-masked tiles are inert: alpha=1, P=0)
// so every __syncthreads is uniformly executed.
// ---------------------------------------------------------------------------
__global__ __launch_bounds__(256, 2) void flash_attn_mfma(
    const ushort* __restrict__ Qsp, const ushort* __restrict__ Ksp,
    const ushort* __restrict__ Vsp, ushort* __restrict__ ctx_h,
    ushort* __restrict__ ctx_l)
{
    __shared__ __align__(16) ushort Ks[32][280];      // hi at 0, lo at 144
    __shared__ __align__(16) unsigned Vt[128][36];    // [feat][kv] hi|lo<<16
    __shared__ __align__(16) unsigned Pw[4][32][36];  // per-wave [q][kv] packed

    const int tid  = threadIdx.x;
    const int wave = tid >> 6;
    const int lane = tid & 63;
    const int l15  = lane & 15;
    const int quad = lane >> 4;
    const int q0   = (gridDim.x - 1 - blockIdx.x) * 128;   // heavy tiles first
    const int h    = blockIdx.y;
    const int b    = blockIdx.z;
    const int kvh  = h >> 2;
    const int wq0  = q0 + wave * 32;

    // ---- Q fragments (B-operand) into registers: [nf][ks][plane] ----
    short8 qf[2][4][2];
#pragma unroll
    for (int nf = 0; nf < 2; ++nf)
#pragma unroll
        for (int ks = 0; ks < 4; ++ks) {
            size_t base = (((size_t)b * S_ + wq0 + nf * 16 + l15) * NH_ + h) * 256
                        + ks * 32 + quad * 8;
            qf[nf][ks][0] = *(const short8*)&Qsp[base];
            qf[nf][ks][1] = *(const short8*)&Qsp[base + 128];
        }

    f32x4 O[2][8];
#pragma unroll
    for (int mf = 0; mf < 2; ++mf)
#pragma unroll
        for (int nf = 0; nf < 8; ++nf) O[mf][nf] = 0.f;
    float m_[2] = {-3.0e38f, -3.0e38f};
    float l_[2] = {0.f, 0.f};

    const int ntiles = q0 / 32 + 4;
    for (int t = 0; t < ntiles; ++t) {
        const int k0 = t * 32;
        __syncthreads();                       // prev tile's LDS reads done

        // ---- stage K (32 rows x 256 ushorts) into padded hi/lo planes ----
#pragma unroll
        for (int i = 0; i < 4; ++i) {
            int c = tid + i * 256;             // 1024 chunks of 8 ushorts
            int row = c >> 5, seg = c & 31;
            const ushort* src = Ksp + (((size_t)b * S_ + k0 + row) * NKV_ + kvh) * 256 + seg * 8;
            ushort* dst = &Ks[row][seg * 8 + (seg >= 16 ? 16 : 0)];
            *(uint4*)dst = *(const uint4*)src;
        }
        // ---- stage V transposed+packed: Vt[feat][kv] = hi | lo<<16 ----
        {
            int row = tid & 31, fs = tid >> 5;
            const ushort* src = Vsp + (((size_t)b * S_ + k0 + row) * NKV_ + kvh) * 256 + fs * 16;
#pragma unroll
            for (int hf = 0; hf < 2; ++hf) {
                uint4 hv = *(const uint4*)(src + hf * 8);
                uint4 lv = *(const uint4*)(src + 128 + hf * 8);
                const ushort* hp = (const ushort*)&hv;
                const ushort* lp = (const ushort*)&lv;
#pragma unroll
                for (int i = 0; i < 8; ++i)
                    Vt[fs * 16 + hf * 8 + i][row] = (unsigned)hp[i] | ((unsigned)lp[i] << 16);
            }
        }
        __syncthreads();

        // ---- S^T = K . Q^T  (rows kv, cols q) ----
        f32x4 st[2][2];                        // [nf(q)][mf(kv)]
#pragma unroll
        for (int nf = 0; nf < 2; ++nf)
#pragma unroll
            for (int mf = 0; mf < 2; ++mf) st[nf][mf] = 0.f;
#pragma unroll
        for (int ks = 0; ks < 4; ++ks) {
            short8 kf_h[2], kf_l[2];
#pragma unroll
            for (int mf = 0; mf < 2; ++mf) {
                kf_h[mf] = *(const short8*)&Ks[mf * 16 + l15][ks * 32 + quad * 8];
                kf_l[mf] = *(const short8*)&Ks[mf * 16 + l15][144 + ks * 32 + quad * 8];
            }
#pragma unroll
            for (int nf = 0; nf < 2; ++nf)
#pragma unroll
                for (int mf = 0; mf < 2; ++mf) {
                    st[nf][mf] = __builtin_amdgcn_mfma_f32_16x16x32_bf16(kf_h[mf], qf[nf][ks][0], st[nf][mf], 0, 0, 0);
                    st[nf][mf] = __builtin_amdgcn_mfma_f32_16x16x32_bf16(kf_h[mf], qf[nf][ks][1], st[nf][mf], 0, 0, 0);
                    st[nf][mf] = __builtin_amdgcn_mfma_f32_16x16x32_bf16(kf_l[mf], qf[nf][ks][0], st[nf][mf], 0, 0, 0);
                }
        }

        // ---- causal mask ----
        if (k0 + 31 > wq0) {
#pragma unroll
            for (int nf = 0; nf < 2; ++nf)
#pragma unroll
                for (int mf = 0; mf < 2; ++mf)
#pragma unroll
                    for (int r = 0; r < 4; ++r) {
                        int kg = k0 + mf * 16 + quad * 4 + r;
                        int qg = wq0 + nf * 16 + l15;
                        if (kg > qg) st[nf][mf][r] = -3.0e38f;
                    }
        }

        // ---- online softmax (per q column; reduce in-lane + across quads) ----
        float alp[2];
#pragma unroll
        for (int nf = 0; nf < 2; ++nf) {
            float rm = -3.0e38f;
#pragma unroll
            for (int mf = 0; mf < 2; ++mf)
#pragma unroll
                for (int r = 0; r < 4; ++r) rm = fmaxf(rm, st[nf][mf][r]);
            rm = fmaxf(rm, __shfl_xor(rm, 16));
            rm = fmaxf(rm, __shfl_xor(rm, 32));
            float mn = fmaxf(m_[nf], rm);
            float a  = __expf(m_[nf] - mn);
            float rs = 0.f;
#pragma unroll
            for (int mf = 0; mf < 2; ++mf)
#pragma unroll
                for (int r = 0; r < 4; ++r) {
                    float p = __expf(st[nf][mf][r] - mn);
                    st[nf][mf][r] = p;
                    rs += p;
                }
            rs += __shfl_xor(rs, 16);
            rs += __shfl_xor(rs, 32);
            l_[nf] = l_[nf] * a + rs;
            m_[nf] = mn;
            alp[nf] = a;
        }

        // ---- rescale O (alpha fetched from owner lane of each q row) ----
#pragma unroll
        for (int omf = 0; omf < 2; ++omf)
#pragma unroll
            for (int r = 0; r < 4; ++r) {
                float av = __shfl(alp[omf], (lane & 48) | (quad * 4 + r));
#pragma unroll
                for (int nf = 0; nf < 8; ++nf) O[omf][nf][r] *= av;
            }

        // ---- P (split+packed) to per-wave LDS in [q][kv] layout ----
#pragma unroll
        for (int nf = 0; nf < 2; ++nf)
#pragma unroll
            for (int mf = 0; mf < 2; ++mf) {
                uint4 w;
                w.x = pack_split(st[nf][mf][0]);
                w.y = pack_split(st[nf][mf][1]);
                w.z = pack_split(st[nf][mf][2]);
                w.w = pack_split(st[nf][mf][3]);
                *(uint4*)&Pw[wave][nf * 16 + l15][mf * 16 + quad * 4] = w;
            }
        __syncthreads();    // hard ordering: P writes visible before reads

        // ---- O += P . V ----
        short8 ph[2], pl[2];
#pragma unroll
        for (int omf = 0; omf < 2; ++omf) {
            const unsigned* pw = &Pw[wave][omf * 16 + l15][quad * 8];
            unsigned w[8];
            *(uint4*)w       = *(const uint4*)pw;
            *(uint4*)(w + 4) = *(const uint4*)(pw + 4);
            unpack8(w, ph[omf], pl[omf]);
        }
#pragma unroll
        for (int vnf = 0; vnf < 8; ++vnf) {
            const unsigned* vw = &Vt[vnf * 16 + l15][quad * 8];
            unsigned w[8];
            *(uint4*)w       = *(const uint4*)vw;
            *(uint4*)(w + 4) = *(const uint4*)(vw + 4);
            short8 vh, vl;
            unpack8(w, vh, vl);
#pragma unroll
            for (int omf = 0; omf < 2; ++omf) {
                O[omf][vnf] = __builtin_amdgcn_mfma_f32_16x16x32_bf16(ph[omf], vh, O[omf][vnf], 0, 0, 0);
                O[omf][vnf] = __builtin_amdgcn_mfma_f32_16x16x32_bf16(ph[omf], vl, O[omf][vnf], 0, 0, 0);
                O[omf][vnf] = __builtin_amdgcn_mfma_f32_16x16x32_bf16(pl[omf], vh, O[omf][vnf], 0, 0, 0);
            }
        }
    }

    // ---- epilogue: normalize, split, store planar ctx ----
    float li[2] = {1.f / l_[0], 1.f / l_[1]};
#pragma unroll
    for (int omf = 0; omf < 2; ++omf)
#pragma unroll
        for (int r = 0; r < 4; ++r) {
            float il = __shfl(li[omf], (lane & 48) | (quad * 4 + r));
            int qrow = wq0 + omf * 16 + quad * 4 + r;
            size_t rowb = ((size_t)b * S_ + qrow) * (size_t)D_ + h * HD_;
#pragma unroll
            for (int nf = 0; nf < 8; ++nf) {
                float val = O[omf][nf][r] * il;
                unsigned short hh, ll; split1(val, hh, ll);
                int feat = nf * 16 + l15;
                ctx_h[rowb + feat] = hh;
                ctx_l[rowb + feat] = ll;
            }
        }
}

// ---------------------------------------------------------------------------
extern "C" void kernel_launch(void* const* d_in, const int* in_sizes, int n_in,
                              void* d_out, int out_size, void* d_ws, size_t ws_size,
                              hipStream_t stream)
{
    const float* x    = (const float*)d_in[0];
    const float* wq_w = (const float*)d_in[1];
    const float* wq_b = (const float*)d_in[2];
    const float* wk_w = (const float*)d_in[3];
    const float* wk_b = (const float*)d_in[4];
    const float* wv_w = (const float*)d_in[5];
    const float* wv_b = (const float*)d_in[6];
    const float* wo_w = (const float*)d_in[7];
    float* out = (float*)d_out;

    const int M = B_ * S_;                        // 8192
    const size_t NX   = (size_t)M * D_;           // 16,777,216
    const size_t NKVE = (size_t)M * NKV_ * HD_;   // 4,194,304
    const size_t NWQ  = (size_t)D_ * D_;
    const size_t NWK  = (size_t)(NKV_ * HD_) * D_;

    // workspace layout
    float*  q   = (float*)d_ws;          // becomes interleaved split Q
    float*  k   = q + NX;                // becomes interleaved split K
    float*  v   = k + NKVE;              // becomes interleaved split V
    ushort* xh  = (ushort*)(v + NKVE);   // x hi split; later ctx_h (planar)
    ushort* xl  = xh + NX;               // x lo split; later ctx_l (planar)
    ushort* wqh = xl + NX;
    ushort* wql = wqh + NWQ;
    ushort* wkh = wql + NWQ;
    ushort* wkl = wkh + NWK;
    ushort* wvh = wkl + NWK;
    ushort* wvl = wvh + NWK;
    ushort* woh = wvl + NWK;
    ushort* wol = woh + NWQ;

    // 1) fp32 -> bf16 hi/lo splits
    split_bf16_k<<<NX  / 1024, 256, 0, stream>>>(x,    xh,  xl);
    split_bf16_k<<<NWQ / 1024, 256, 0, stream>>>(wq_w, wqh, wql);
    split_bf16_k<<<NWK / 1024, 256, 0, stream>>>(wk_w, wkh, wkl);
    split_bf16_k<<<NWK / 1024, 256, 0, stream>>>(wv_w, wvh, wvl);
    split_bf16_k<<<NWQ / 1024, 256, 0, stream>>>(wo_w, woh, wol);

    // 2) QKV projections (fp32 outputs)
    gemm_mfma_split<<<dim3(D_/128,         M/128), 256, 0, stream>>>(xh, xl, wqh, wql, wq_b, q, M, D_,       D_);
    gemm_mfma_split<<<dim3((NKV_*HD_)/128, M/128), 256, 0, stream>>>(xh, xl, wkh, wkl, wk_b, k, M, NKV_*HD_, D_);
    gemm_mfma_split<<<dim3((NKV_*HD_)/128, M/128), 256, 0, stream>>>(xh, xl, wvh, wvl, wv_b, v, M, NKV_*HD_, D_);

    // 3) RoPE (+ scale into Q) and in-place interleaved hi/lo split
    rope_split_kernel<<<(M * NH_)  / 2, 256, 0, stream>>>(q, NH_,  0.08838834764831845f, 1);
    rope_split_kernel<<<(M * NKV_) / 2, 256, 0, stream>>>(k, NKV_, 1.0f, 1);
    rope_split_kernel<<<(M * NKV_) / 2, 256, 0, stream>>>(v, NKV_, 1.0f, 0);

    // 4) MFMA flash attention -> planar ctx hi/lo (x splits are dead now)
    flash_attn_mfma<<<dim3(S_/128, NH_, B_), 256, 0, stream>>>(
        (const ushort*)q, (const ushort*)k, (const ushort*)v, xh, xl);

    // 5) output projection (round-3-verified planar path)
    gemm_mfma_split<<<dim3(D_/128, M/128), 256, 0, stream>>>(xh, xl, woh, wol, nullptr, out, M, D_, D_);
}